// Round 12
// baseline (351.673 us; speedup 1.0000x reference)
//
#include <hip/hip_runtime.h>

typedef _Float16 f16x8 __attribute__((ext_vector_type(8)));
typedef float    f32x4 __attribute__((ext_vector_type(4)));

constexpr int BATCH = 2048;
constexpr int SEQ   = 512;
constexpr int H     = 50;
constexpr int NB    = 8;     // batch per block -> 256 blocks = 1 per CU
constexpr int NT    = 896;   // 14 waves: 7 L0 + 7 L1, lockstep barrier
constexpr int KQ    = 4;     // panel k-chunks of 32 (K=128)
constexpr int PSZ   = KQ * 64 * 8;   // panel halfs (2048 = 4 KB)

__device__ __forceinline__ float fexp2(float x) { return __builtin_amdgcn_exp2f(x); }
__device__ __forceinline__ float frcp(float x)  { return __builtin_amdgcn_rcpf(x); }
// B-panel frag-linear address (halfs) for value (k, n), k<128, n<16
__device__ __forceinline__ int baddr(int k, int n) {
    return (((k >> 5) * 64) + (((k >> 3) & 3) * 16) + n) * 8 + (k & 7);
}

constexpr float K1 = 1.4426950408889634f;   // log2(e)
constexpr float K2 = 2.8853900817779268f;   // 2*log2(e)

// Panel k-map (hi-only f16 h, x REMOVED from panel):
//   k in [0,50):   h1 unit j=k      (chunks 0-1; 50..63 pad = 0)
//   k in [64,114): h2 unit j=k-64   (chunks 2-3; 114..127 pad = 0)
// x is applied in the L0 combine as 4 exact f32 FMAs (wx[gate]*x_t).
// Columns 8..15 duplicate batches 0..7 (L0/L1-merge via cndmask, no bpermute).
// GATE PERM (r9/r11): tile m phys row w <-> jj = 4m+(w>>2), gate w&3; after
// MFMA lane (quad,nn) reg r = gate r of hidden jj = 4m+quad, batch nn ->
// combine runs in-register in the owning lane.
// LAYER-SPLIT WAVES (lockstep): waves 0..6 = L0, tiles 2g,2g+1, read ONLY
// chunks 0-1 (h1) -> 2 ds_read_b128; waves 7..13 = L1, tiles 2g,2g+1, read
// chunks 0-3 -> 4 reads.  DS read volume 52->42 KB/step.
// Schedule (1 barrier/step): iter s reads sB[s&1] = {h1(s-1), h2(s-2)},
// writes sB[(s+1)&1] = {h1(s), h2(s-1)}.  Unroll-2 -> compile-time panel
// pointers; edges (s=0,511,512) peeled via doL0/doL1 flags.

__global__ __launch_bounds__(NT, 4) void lstm2_split(
    const float* __restrict__ x,
    const float* __restrict__ Wih0, const float* __restrict__ Whh0,
    const float* __restrict__ bih0, const float* __restrict__ bhh0,
    const float* __restrict__ Wih1, const float* __restrict__ Whh1,
    const float* __restrict__ bih1, const float* __restrict__ bhh1,
    const float* __restrict__ fcW,  const float* __restrict__ fcb,
    float* __restrict__ out)
{
    __shared__ _Float16 sB[2][PSZ];     // double-buffered panel, 8 KB
    __shared__ float    sX32[SEQ * NB]; // raw f32 x, 16 KB
    __shared__ float    sH2f[H * NB];   // final h2

    const int t    = threadIdx.x;
    const int wave = t >> 6, lane = t & 63;
    const int quad = lane >> 4, nn = lane & 15;
    const int bbase = blockIdx.x * NB;

    // zero both panels (pads must stay 0 forever)
    for (int i = t; i < 2 * PSZ; i += NT) ((_Float16*)sB)[i] = (_Float16)0.f;
    // stage ALL x as raw f32 (coalesced)
    for (int i = t; i < NB * SEQ; i += NT) {
        const int b = i >> 9, s = i & (SEQ - 1);
        sX32[s * NB + b] = x[(bbase + b) * SEQ + s];
    }

    const bool isL0 = (wave < 7);
    const int  g    = isL0 ? wave : wave - 7;     // group 0..6, tiles 2g,2g+1
    const bool t2v  = (8 * g + 4 < H);            // tile 2g+1 has live rows?

    // ---- constant A-fragments (gate-permuted rows) ----
    f16x8 a0[2][2];   // L0 waves: chunks 0-1
    f16x8 a1[2][4];   // L1 waves: chunks 0-3
    f32x4 bv[2];
    #pragma unroll
    for (int i = 0; i < 2; ++i) {
        const int  ti   = 2 * g + i;
        const int  jr   = ti * 4 + (nn >> 2);     // hidden unit of A phys row nn
        const int  gate = nn & 3;
        const bool rv   = (jr < H);
        const int  lrow = gate * H + jr;          // logical W row
        if (isL0) {
            #pragma unroll
            for (int q = 0; q < 2; ++q)
                #pragma unroll
                for (int j = 0; j < 8; ++j) {
                    const int k = q * 32 + quad * 8 + j;
                    a0[i][q][j] = (rv && k < 50) ? (_Float16)Whh0[lrow * H + k]
                                                 : (_Float16)0.f;
                }
        } else {
            #pragma unroll
            for (int q = 0; q < 4; ++q)
                #pragma unroll
                for (int j = 0; j < 8; ++j) {
                    const int k = q * 32 + quad * 8 + j;
                    _Float16 v = (_Float16)0.f;
                    if (rv) {
                        if      (k < 50)              v = (_Float16)Wih1[lrow * H + k];
                        else if (k >= 64 && k < 114)  v = (_Float16)Whh1[lrow * H + (k - 64)];
                    }
                    a1[i][q][j] = v;
                }
        }
        const int jq = ti * 4 + quad;
        #pragma unroll
        for (int r = 0; r < 4; ++r) {
            const bool bvv = (jq < H);
            bv[i][r] = !bvv ? 0.f
                     : (isL0 ? (bih0[r * H + jq] + bhh0[r * H + jq])
                             : (bih1[r * H + jq] + bhh1[r * H + jq]));
        }
    }

    // per-lane combine identity: lanes nn<8 -> tile 2g, nn>=8 -> tile 2g+1
    const bool hiT  = (nn >= 8);
    const int  jj   = 8 * g + (hiT ? 4 : 0) + quad;  // hidden unit
    const int  col  = nn & 7;                        // batch
    const bool wrOK = (jj < H);
    const int  kb   = isL0 ? jj : (64 + jj);
    const int  wH0  = baddr(kb, col);
    const int  wH1  = baddr(kb, col + 8);
    float wx[4];
    #pragma unroll
    for (int r = 0; r < 4; ++r)
        wx[r] = (isL0 && wrOK) ? Wih0[r * H + jj] : 0.f;   // INPUT_SIZE == 1
    float c = 0.f;

    __syncthreads();

    auto body = [&](int s, const _Float16* __restrict__ br,
                    _Float16* __restrict__ bw,
                    bool doL0, bool doL1, bool last) {
        if (isL0) {
            f16x8 b0 = *(const f16x8*)&br[(0 * 64 + lane) * 8];
            f16x8 b1 = *(const f16x8*)&br[(1 * 64 + lane) * 8];
            f32x4 A = bv[0], B = bv[1];
            A = __builtin_amdgcn_mfma_f32_16x16x32_f16(a0[0][0], b0, A, 0, 0, 0);
            A = __builtin_amdgcn_mfma_f32_16x16x32_f16(a0[0][1], b1, A, 0, 0, 0);
            if (t2v) {
                B = __builtin_amdgcn_mfma_f32_16x16x32_f16(a0[1][0], b0, B, 0, 0, 0);
                B = __builtin_amdgcn_mfma_f32_16x16x32_f16(a0[1][1], b1, B, 0, 0, 0);
            }
            if (doL0) {
                f32x4 gg;
                #pragma unroll
                for (int r = 0; r < 4; ++r) gg[r] = hiT ? B[r] : A[r];
                const float xv = sX32[s * NB + col];
                #pragma unroll
                for (int r = 0; r < 4; ++r) gg[r] = fmaf(wx[r], xv, gg[r]);
                float Ei = fexp2(-K1 * gg[0]);
                float Ef = fexp2(-K1 * gg[1]);
                float Eg = fexp2(-K2 * fabsf(gg[2]));
                float Eo = fexp2(-K1 * gg[3]);
                float it = copysignf((1.f - Eg) * frcp((1.f + Ei) * (1.f + Eg)), gg[2]);
                c = frcp(1.f + Ef) * c + it;
                float Ec = fexp2(-K2 * fabsf(c));
                float h  = copysignf((1.f - Ec) * frcp((1.f + Eo) * (1.f + Ec)), c);
                if (wrOK) {
                    _Float16 hh = (_Float16)h;
                    bw[wH0] = hh;
                    bw[wH1] = hh;
                }
            }
        } else {
            f16x8 bq[4];
            #pragma unroll
            for (int q = 0; q < 4; ++q)
                bq[q] = *(const f16x8*)&br[(q * 64 + lane) * 8];
            f32x4 A = bv[0], B = bv[1];
            #pragma unroll
            for (int q = 0; q < 4; ++q)
                A = __builtin_amdgcn_mfma_f32_16x16x32_f16(a1[0][q], bq[q], A, 0, 0, 0);
            if (t2v) {
                #pragma unroll
                for (int q = 0; q < 4; ++q)
                    B = __builtin_amdgcn_mfma_f32_16x16x32_f16(a1[1][q], bq[q], B, 0, 0, 0);
            }
            if (doL1) {
                f32x4 gg;
                #pragma unroll
                for (int r = 0; r < 4; ++r) gg[r] = hiT ? B[r] : A[r];
                float Ei = fexp2(-K1 * gg[0]);
                float Ef = fexp2(-K1 * gg[1]);
                float Eg = fexp2(-K2 * fabsf(gg[2]));
                float Eo = fexp2(-K1 * gg[3]);
                float it = copysignf((1.f - Eg) * frcp((1.f + Ei) * (1.f + Eg)), gg[2]);
                c = frcp(1.f + Ef) * c + it;
                float Ec = fexp2(-K2 * fabsf(c));
                float h  = copysignf((1.f - Ec) * frcp((1.f + Eo) * (1.f + Ec)), c);
                if (wrOK) {
                    if (last) {
                        sH2f[jj * NB + col] = h;     // h2(511) for the FC
                    } else {
                        _Float16 hh = (_Float16)h;
                        bw[wH0] = hh;
                        bw[wH1] = hh;
                    }
                }
            }
        }
        __syncthreads();   // the ONLY barrier per step
    };

    body(0, sB[0], sB[1], true, false, false);
    #pragma unroll 1
    for (int i = 0; i < 255; ++i) {
        body(2 * i + 1, sB[1], sB[0], true, true, false);
        body(2 * i + 2, sB[0], sB[1], true, true, false);
    }
    body(511, sB[1], sB[0], true, true, false);
    body(512, sB[0], sB[1], false, true, true);

    // ---- FC epilogue: out[b] = fcW . h2_last[b] + fcb ----
    if (t < NB) {
        float sum = fcb[0];
        #pragma unroll
        for (int jx = 0; jx < H; ++jx) sum += fcW[jx] * sH2f[jx * NB + t];
        out[bbase + t] = sum;
    }
}

extern "C" void kernel_launch(void* const* d_in, const int* in_sizes, int n_in,
                              void* d_out, int out_size, void* d_ws, size_t ws_size,
                              hipStream_t stream)
{
    const float* x    = (const float*)d_in[0];
    const float* Wih0 = (const float*)d_in[1];
    const float* Whh0 = (const float*)d_in[2];
    const float* bih0 = (const float*)d_in[3];
    const float* bhh0 = (const float*)d_in[4];
    const float* Wih1 = (const float*)d_in[5];
    const float* Whh1 = (const float*)d_in[6];
    const float* bih1 = (const float*)d_in[7];
    const float* bhh1 = (const float*)d_in[8];
    const float* fcW  = (const float*)d_in[9];
    const float* fcb  = (const float*)d_in[10];

    lstm2_split<<<BATCH / NB, NT, 0, stream>>>(
        x, Wih0, Whh0, bih0, bhh0, Wih1, Whh1, bih1, bhh1, fcW, fcb,
        (float*)d_out);
}

// Round 13
// 344.226 us; speedup vs baseline: 1.0216x; 1.0216x over previous
//
#include <hip/hip_runtime.h>

typedef _Float16 f16x8 __attribute__((ext_vector_type(8)));
typedef float    f32x4 __attribute__((ext_vector_type(4)));

constexpr int BATCH = 2048;
constexpr int SEQ   = 512;
constexpr int H     = 50;
constexpr int NB    = 8;     // batch per block -> 256 blocks = 1 per CU
constexpr int NT    = 1024;  // 16 waves (13 compute + 3 idle), 4 per SIMD
constexpr int KQ    = 2;     // panel k-chunks of 32 (K=64)
constexpr int PSZ   = KQ * 64 * 8;   // panel halfs (1024 = 2 KB)

__device__ __forceinline__ float fexp2(float x) { return __builtin_amdgcn_exp2f(x); }
__device__ __forceinline__ float frcp(float x)  { return __builtin_amdgcn_rcpf(x); }
// frag-linear address (halfs) for value (k, n), k<64, n<16
__device__ __forceinline__ int baddr(int k, int n) {
    return (((k >> 5) * 64) + (((k >> 3) & 3) * 16) + n) * 8 + (k & 7);
}
union FI { float f; int i; };
// xor-8 within each 16-lane row: row_ror:8 (ctrl 0x128), pure VALU (no DS)
__device__ __forceinline__ float dpp_xor8(float v) {
    FI u; u.f = v;
    FI r; r.i = __builtin_amdgcn_mov_dpp(u.i, 0x128, 0xf, 0xf, true);
    return r.f;
}

constexpr float K1 = 1.4426950408889634f;   // log2(e)
constexpr float K2 = 2.8853900817779268f;   // 2*log2(e)

// Panel (K=64, 2 chunks): k in [0,50) = hidden unit j=k; k [50,64) pad 0.
//   columns 0..7  = h1[j][batch n]     columns 8..15 = h2[j][batch n-8]
// L0: g0 = MFMA(Whh0, panel) -> cols 0..7 valid (+ x via exact f32 fmaf).
// L1: P = MFMA(Wih1, panel) -> cols 0..7 = Wih1.h1;  Q = MFMA(Whh1, panel)
//     (bias in Q init) -> cols 8..15 = Whh1.h2.  g1[b] = P[col b] + Q[col b+8]
//     -> hi lanes add dpp_xor8(P) to their own Q.  No bpermute, no dup writes.
// GATE PERM (r9..r12): tile m phys row w <-> jj = 4m+(w>>2), gate w&3; after
// MFMA lane (quad,nn) reg r = gate r of hidden jj = 4m+quad, col nn.  Lanes
// nn<8 combine L0 (batch nn), lanes nn>=8 combine L1 (batch nn-8); each lane
// writes ONE f16 h at (k=jj, n=nn) -- its own column.
// Schedule (1 barrier/step, r11 skeleton): iter s reads sB[s&1] =
// {h1(s-1), h2(s-2)}, writes sB[(s+1)&1] = {h1(s), h2(s-1)}.  Unroll-2,
// edges s=0,511,512 peeled.

__global__ __launch_bounds__(NT, 4) void lstm2_cs(
    const float* __restrict__ x,
    const float* __restrict__ Wih0, const float* __restrict__ Whh0,
    const float* __restrict__ bih0, const float* __restrict__ bhh0,
    const float* __restrict__ Wih1, const float* __restrict__ Whh1,
    const float* __restrict__ bih1, const float* __restrict__ bhh1,
    const float* __restrict__ fcW,  const float* __restrict__ fcb,
    float* __restrict__ out)
{
    __shared__ _Float16 sB[2][PSZ];     // double-buffered panel, 4 KB total
    __shared__ float    sX32[SEQ * NB]; // raw f32 x, 16 KB
    __shared__ float    sH2f[H * NB];   // final h2

    const int t    = threadIdx.x;
    const int wave = t >> 6, lane = t & 63;
    const int quad = lane >> 4, nn = lane & 15;
    const int bbase = blockIdx.x * NB;

    // zero both panels (pads must stay 0 forever)
    for (int i = t; i < 2 * PSZ; i += NT) ((_Float16*)sB)[i] = (_Float16)0.f;
    // stage ALL x as raw f32 (coalesced)
    for (int i = t; i < NB * SEQ; i += NT) {
        const int b = i >> 9, s = i & (SEQ - 1);
        sX32[s * NB + b] = x[(bbase + b) * SEQ + s];
    }

    // ---- constant A-fragments; wave w owns tile m = w (13 active waves) ----
    const bool mmv = (wave < 13);
    f16x8 a0[KQ];   // Whh0  (L0)
    f16x8 aP[KQ];   // Wih1  (L1 input part)
    f16x8 aQ[KQ];   // Whh1  (L1 recurrent part)
    f32x4 b0v = {0,0,0,0}, b1v = {0,0,0,0};
    if (mmv) {
        const int  m    = wave;
        const int  jr   = m * 4 + (nn >> 2);     // hidden unit of A phys row nn
        const int  gate = nn & 3;
        const bool rv   = (jr < H);
        const int  lrow = gate * H + jr;         // logical W row
        #pragma unroll
        for (int q = 0; q < KQ; ++q) {
            #pragma unroll
            for (int j = 0; j < 8; ++j) {
                const int k = q * 32 + quad * 8 + j;
                const bool kv = rv && (k < 50);
                a0[q][j] = kv ? (_Float16)Whh0[lrow * H + k] : (_Float16)0.f;
                aP[q][j] = kv ? (_Float16)Wih1[lrow * H + k] : (_Float16)0.f;
                aQ[q][j] = kv ? (_Float16)Whh1[lrow * H + k] : (_Float16)0.f;
            }
        }
        const int jq = m * 4 + quad;
        #pragma unroll
        for (int r = 0; r < 4; ++r) {
            const bool bv = (jq < H);
            b0v[r] = bv ? (bih0[r * H + jq] + bhh0[r * H + jq]) : 0.f;
            b1v[r] = bv ? (bih1[r * H + jq] + bhh1[r * H + jq]) : 0.f;
        }
    }

    // per-lane combine identity
    const int  jj   = wave * 4 + quad;        // hidden unit (valid < 50)
    const bool hiH  = (nn >= 8);              // hi lanes combine L1
    const int  col  = nn & 7;                 // batch
    const bool wrOK = mmv && (jj < H);
    const int  wH   = baddr(jj, nn);          // own column -> single write
    float wx[4];
    #pragma unroll
    for (int r = 0; r < 4; ++r)
        wx[r] = wrOK ? Wih0[r * H + jj] : 0.f;     // INPUT_SIZE == 1, exact
    float c = 0.f;                            // c0 (lo lanes) or c1 (hi lanes)

    __syncthreads();

    auto body = [&](int s, const _Float16* __restrict__ br,
                    _Float16* __restrict__ bw,
                    bool doL0, bool doL1, bool last) {
        if (mmv) {
            f16x8 b0 = *(const f16x8*)&br[(0 * 64 + lane) * 8];
            f16x8 b1 = *(const f16x8*)&br[(1 * 64 + lane) * 8];

            f32x4 g0 = b0v;                       // L0 gates (cols 0..7 valid)
            g0 = __builtin_amdgcn_mfma_f32_16x16x32_f16(a0[0], b0, g0, 0, 0, 0);
            g0 = __builtin_amdgcn_mfma_f32_16x16x32_f16(a0[1], b1, g0, 0, 0, 0);
            f32x4 P = {0.f, 0.f, 0.f, 0.f};       // Wih1.h1 (cols 0..7 valid)
            P = __builtin_amdgcn_mfma_f32_16x16x32_f16(aP[0], b0, P, 0, 0, 0);
            P = __builtin_amdgcn_mfma_f32_16x16x32_f16(aP[1], b1, P, 0, 0, 0);
            f32x4 Q = b1v;                        // Whh1.h2+b1 (cols 8..15)
            Q = __builtin_amdgcn_mfma_f32_16x16x32_f16(aQ[0], b0, Q, 0, 0, 0);
            Q = __builtin_amdgcn_mfma_f32_16x16x32_f16(aQ[1], b1, Q, 0, 0, 0);

            const float xv = sX32[s * NB + col];
            f32x4 g;
            #pragma unroll
            for (int r = 0; r < 4; ++r) {
                float gHi = Q[r] + dpp_xor8(P[r]);          // L1: P from lane-8
                float gLo = fmaf(wx[r], xv, g0[r]);          // L0: + exact x
                g[r] = hiH ? gHi : gLo;
            }

            const bool act = hiH ? doL1 : doL0;
            if (act) {
                float Ei = fexp2(-K1 * g[0]);
                float Ef = fexp2(-K1 * g[1]);
                float Eg = fexp2(-K2 * fabsf(g[2]));
                float Eo = fexp2(-K1 * g[3]);
                float it = copysignf((1.f - Eg) * frcp((1.f + Ei) * (1.f + Eg)), g[2]);
                c = frcp(1.f + Ef) * c + it;
                float Ec = fexp2(-K2 * fabsf(c));
                float h  = copysignf((1.f - Ec) * frcp((1.f + Eo) * (1.f + Ec)), c);
                if (wrOK) {
                    if (last && hiH) sH2f[jj * NB + col] = h;   // h2(511)
                    else             bw[wH] = (_Float16)h;      // one b16 write
                }
            }
        }
        __syncthreads();   // the ONLY barrier per step
    };

    body(0, sB[0], sB[1], true, false, false);
    #pragma unroll 1
    for (int i = 0; i < 255; ++i) {
        body(2 * i + 1, sB[1], sB[0], true, true, false);
        body(2 * i + 2, sB[0], sB[1], true, true, false);
    }
    body(511, sB[1], sB[0], true, true, false);
    body(512, sB[0], sB[1], false, true, true);

    // ---- FC epilogue: out[b] = fcW . h2_last[b] + fcb ----
    if (t < NB) {
        float sum = fcb[0];
        #pragma unroll
        for (int jx = 0; jx < H; ++jx) sum += fcW[jx] * sH2f[jx * NB + t];
        out[bbase + t] = sum;
    }
}

extern "C" void kernel_launch(void* const* d_in, const int* in_sizes, int n_in,
                              void* d_out, int out_size, void* d_ws, size_t ws_size,
                              hipStream_t stream)
{
    const float* x    = (const float*)d_in[0];
    const float* Wih0 = (const float*)d_in[1];
    const float* Whh0 = (const float*)d_in[2];
    const float* bih0 = (const float*)d_in[3];
    const float* bhh0 = (const float*)d_in[4];
    const float* Wih1 = (const float*)d_in[5];
    const float* Whh1 = (const float*)d_in[6];
    const float* bih1 = (const float*)d_in[7];
    const float* bhh1 = (const float*)d_in[8];
    const float* fcW  = (const float*)d_in[9];
    const float* fcb  = (const float*)d_in[10];

    lstm2_cs<<<BATCH / NB, NT, 0, stream>>>(
        x, Wih0, Whh0, bih0, bhh0, Wih1, Whh1, bih1, bhh1, fcW, fcb,
        (float*)d_out);
}

// Round 15
// 322.123 us; speedup vs baseline: 1.0917x; 1.0686x over previous
//
#include <hip/hip_runtime.h>

typedef _Float16 f16x8 __attribute__((ext_vector_type(8)));
typedef float    f32x4 __attribute__((ext_vector_type(4)));

constexpr int BATCH = 2048;
constexpr int SEQ   = 512;
constexpr int H     = 50;
constexpr int NB    = 8;     // batch per block -> 256 blocks = 1 per CU
constexpr int NT    = 1024;  // 16 waves, 4 per SIMD
constexpr int KQ    = 4;     // panel k-chunks of 32 (K=128)
constexpr int PSZ   = KQ * 64 * 8;   // panel halfs (2048 = 4 KB)

__device__ __forceinline__ float fexp2(float x) { return __builtin_amdgcn_exp2f(x); }
__device__ __forceinline__ float frcp(float x)  { return __builtin_amdgcn_rcpf(x); }
__device__ __forceinline__ _Float16 f16hi(float w) { return (_Float16)w; }
__device__ __forceinline__ _Float16 f16lo(float w) {
    _Float16 h = (_Float16)w; return (_Float16)(w - (float)h);
}
// B-panel frag-linear address (halfs) for value (k, n), k<128, n<16
__device__ __forceinline__ int baddr(int k, int n) {
    return (((k >> 5) * 64) + (((k >> 3) & 3) * 16) + n) * 8 + (k & 7);
}
union H2U { unsigned u; _Float16 h[2]; };

constexpr float K1 = 1.4426950408889634f;   // log2(e)
constexpr float K2 = 2.8853900817779268f;   // 2*log2(e)

// Panel k-map (HI-ONLY f16 h, 4 chunks):
//   k in [0,50):   h1 unit j=k (single f16)
//   k 50,51:       x_hi, x_lo  (x exact: A rows hold wx_hi/wx_lo)
//   k [52,64):     zero pad
//   k [64,114):    h2 unit j=k-64 (single f16)
//   k [114,128):   zero pad
// Columns 8..15 duplicate batches 0..7 (kills the L0/L1 merge bpermute).
// GATE PERM (r9): tile m phys row w <-> jj = 4m+(w>>2), gate w&3; after MFMA
// lane (quad,nn) reg r = gate r of hidden jj = 4m+quad, batch nn -> combine
// runs in-register in the owning lane (lanes nn<8: L0; nn>=8: L1).
// Schedule (1 barrier/step): iter s reads sB[s&1] = {h1(s-1), x(s), h2(s-2)},
// writes sB[(s+1)&1] = {h1(s), x(s+1), h2(s-1)}.  Unroll-2 -> compile-time
// panel pointers; edges (s=0,511,512) peeled.
// Precision: w,h products carry ~2*2^-11 rel error; biases/x exact;
// c-recurrence in f32.  Measured absmax 4.88e-4 (threshold 1.63e-3).
// NOTE (r12/r13/r14 post-mortems): DS-volume cuts and de-phasing variants all
// regressed or broke -- this minimum-issue lockstep structure is the verified
// optimum of the family.

__global__ __launch_bounds__(NT, 4) void lstm2_hi(
    const float* __restrict__ x,
    const float* __restrict__ Wih0, const float* __restrict__ Whh0,
    const float* __restrict__ bih0, const float* __restrict__ bhh0,
    const float* __restrict__ Wih1, const float* __restrict__ Whh1,
    const float* __restrict__ bih1, const float* __restrict__ bhh1,
    const float* __restrict__ fcW,  const float* __restrict__ fcb,
    float* __restrict__ out)
{
    __shared__ _Float16 sB[2][PSZ];     // double-buffered panel, 8 KB
    __shared__ unsigned sXu[SEQ * NB];  // pre-split x (hi,lo), 16 KB
    __shared__ float    sH2f[H * NB];   // final h2

    const int t    = threadIdx.x;
    const int wave = t >> 6, lane = t & 63;
    const int quad = lane >> 4, nn = lane & 15;
    const int bbase = blockIdx.x * NB;

    // zero both panels (pads must stay 0 forever)
    for (int i = t; i < 2 * PSZ; i += NT) ((_Float16*)sB)[i] = (_Float16)0.f;

    // ---- pre-stage ALL x as packed f16 hi/lo pairs (coalesced) ----
    for (int i = t; i < NB * SEQ; i += NT) {
        const int b = i >> 9, s = i & (SEQ - 1);
        float xv = x[(bbase + b) * SEQ + s];
        H2U p; p.h[0] = f16hi(xv); p.h[1] = f16lo(xv);
        sXu[s * NB + b] = p.u;
    }

    // ---- constant A-fragments; wave w owns tile m = w (13 active waves) ----
    const bool mmv = (wave < 13);
    f16x8 a0[2];       // L0: chunks 0..1 (K=64)
    f16x8 a1[KQ];      // L1: chunks 0..3 (K=128)
    f32x4 b0v = {0,0,0,0}, b1v = {0,0,0,0};
    if (mmv) {
        const int  m    = wave;
        const int  jr   = m * 4 + (nn >> 2);     // hidden unit of A phys row nn
        const int  gate = nn & 3;
        const bool rv   = (jr < H);
        const int  lrow = gate * H + jr;         // logical W row
        #pragma unroll
        for (int q = 0; q < 2; ++q) {
            #pragma unroll
            for (int j = 0; j < 8; ++j) {
                const int k = q * 32 + quad * 8 + j;
                _Float16 v = (_Float16)0.f;
                if (rv) {
                    if      (k < 50)   v = (_Float16)Whh0[lrow * H + k];
                    else if (k == 50)  v = f16hi(Wih0[lrow]);
                    else if (k == 51)  v = f16lo(Wih0[lrow]);
                }
                a0[q][j] = v;
            }
        }
        #pragma unroll
        for (int q = 0; q < KQ; ++q) {
            #pragma unroll
            for (int j = 0; j < 8; ++j) {
                const int k = q * 32 + quad * 8 + j;
                _Float16 v = (_Float16)0.f;
                if (rv) {
                    if      (k < 50)              v = (_Float16)Wih1[lrow * H + k];
                    else if (k >= 64 && k < 114)  v = (_Float16)Whh1[lrow * H + (k - 64)];
                }
                a1[q][j] = v;
            }
        }
        const int jq = m * 4 + quad;
        #pragma unroll
        for (int r = 0; r < 4; ++r) {
            const bool bv = (jq < H);
            b0v[r] = bv ? (bih0[r * H + jq] + bhh0[r * H + jq]) : 0.f;
            b1v[r] = bv ? (bih1[r * H + jq] + bhh1[r * H + jq]) : 0.f;
        }
    }

    // per-lane combine identity
    const int  jj   = wave * 4 + quad;        // hidden unit (valid < 50)
    const bool hiH  = (nn >= 8);              // hi lanes combine L1
    const int  col  = nn & 7;                 // batch
    const int  kb   = hiH ? (64 + jj) : jj;   // this lane's h row in the panel
    const int  wH0  = baddr(kb, col);         // half slot, column copy 0
    const int  wH1  = baddr(kb, col + 8);     // half slot, column copy 1
    const bool wrOK = mmv && (jj < H);
    float c = 0.f;                            // c0 (lo lanes) or c1 (hi lanes)

    // x-staging lane constants (wave 15, lanes 0..15 cover both copies)
    const int xcol = lane & 7;
    const int xad  = baddr(50, (lane & 7) + 8 * ((lane >> 3) & 1)) >> 1; // u32 idx

    __syncthreads();
    if (t < 16)                               // x(0), both column copies
        ((unsigned*)sB[0])[baddr(50, (t & 7) + 8 * (t >> 3)) >> 1] = sXu[t & 7];
    __syncthreads();

    auto body = [&](int s, const _Float16* __restrict__ br,
                    _Float16* __restrict__ bw,
                    bool doL0, bool doL1, bool doX, bool last) {
        if (mmv) {
            f16x8 bq[KQ];
            #pragma unroll
            for (int q = 0; q < KQ; ++q)
                bq[q] = *(const f16x8*)&br[(q * 64 + lane) * 8];

            f32x4 g0 = b0v;
            #pragma unroll
            for (int q = 0; q < 2; ++q)
                g0 = __builtin_amdgcn_mfma_f32_16x16x32_f16(a0[q], bq[q], g0, 0, 0, 0);
            f32x4 g1 = b1v;
            #pragma unroll
            for (int q = 0; q < KQ; ++q)
                g1 = __builtin_amdgcn_mfma_f32_16x16x32_f16(a1[q], bq[q], g1, 0, 0, 0);

            f32x4 g;
            #pragma unroll
            for (int r = 0; r < 4; ++r) g[r] = hiH ? g1[r] : g0[r];

            const bool act = hiH ? doL1 : doL0;
            if (act) {
                float Ei = fexp2(-K1 * g[0]);
                float Ef = fexp2(-K1 * g[1]);
                float Eg = fexp2(-K2 * fabsf(g[2]));
                float Eo = fexp2(-K1 * g[3]);
                float it = copysignf((1.f - Eg) * frcp((1.f + Ei) * (1.f + Eg)), g[2]);
                c = frcp(1.f + Ef) * c + it;
                float Ec = fexp2(-K2 * fabsf(c));
                float h  = copysignf((1.f - Ec) * frcp((1.f + Eo) * (1.f + Ec)), c);
                if (wrOK) {
                    if (last && hiH) {
                        sH2f[jj * NB + col] = h;        // h2(511) for the FC
                    } else {
                        _Float16 hh = (_Float16)h;
                        bw[wH0] = hh;                   // column copy 0
                        bw[wH1] = hh;                   // column copy 1
                    }
                }
            }
        } else if (doX && wave == 15 && lane < 16) {
            ((unsigned*)bw)[xad] = sXu[(s + 1) * NB + xcol];
        }
        __syncthreads();   // the ONLY barrier per step
    };

    body(0, sB[0], sB[1], true, false, true, false);
    #pragma unroll 1
    for (int i = 0; i < 255; ++i) {
        body(2 * i + 1, sB[1], sB[0], true, true, true, false);
        body(2 * i + 2, sB[0], sB[1], true, true, true, false);
    }
    body(511, sB[1], sB[0], true, true, false, false);
    body(512, sB[0], sB[1], false, true, false, true);

    // ---- FC epilogue: out[b] = fcW . h2_last[b] + fcb ----
    if (t < NB) {
        float sum = fcb[0];
        #pragma unroll
        for (int jx = 0; jx < H; ++jx) sum += fcW[jx] * sH2f[jx * NB + t];
        out[bbase + t] = sum;
    }
}

extern "C" void kernel_launch(void* const* d_in, const int* in_sizes, int n_in,
                              void* d_out, int out_size, void* d_ws, size_t ws_size,
                              hipStream_t stream)
{
    const float* x    = (const float*)d_in[0];
    const float* Wih0 = (const float*)d_in[1];
    const float* Whh0 = (const float*)d_in[2];
    const float* bih0 = (const float*)d_in[3];
    const float* bhh0 = (const float*)d_in[4];
    const float* Wih1 = (const float*)d_in[5];
    const float* Whh1 = (const float*)d_in[6];
    const float* bih1 = (const float*)d_in[7];
    const float* bhh1 = (const float*)d_in[8];
    const float* fcW  = (const float*)d_in[9];
    const float* fcb  = (const float*)d_in[10];

    lstm2_hi<<<BATCH / NB, NT, 0, stream>>>(
        x, Wih0, Whh0, bih0, bhh0, Wih1, Whh1, bih1, bhh1, fcW, fcb,
        (float*)d_out);
}